// Round 1
// baseline (67.866 us; speedup 1.0000x reference)
//
#include <hip/hip_runtime.h>

// MaxMinComp: out[b,o] = max_i min(x[b,i], W[i,o]); B=1024, IN=OUT=512, fp32.
// fp16 packed-u16 tropical GEMM (values in [0,1) => IEEE order == u16 order).
//
// R5 steady-state 14.25us/rep: VALU ~4.2us, LDS-read ~3.8us + writes/epilogue,
// ~8us stall. LDS-instr-bound: 3 ds_read_b128 per 4096 MACs.
// R6: half-wave k-split (32 slices), per-lane micro-tile 8 rows x 8 cols:
//  - 4 ds_read_b128 per 8192 MACs (-33% LDS read instrs) -> VALU-bound.
//  - x reads stay tx-broadcast; both halves share xor mask (kp&28 invariant
//    under +2) -> all reads <=2-way bank-aliased (free).
//  - 32 -> 16 partials folded in-register via v_permlane32_swap_b32 + pk_max
//    (VALU pipe), keeping the 16-slice / 64KB epilogue overlay unchanged.

typedef unsigned int u32;
typedef u32 u32x2 __attribute__((ext_vector_type(2)));
typedef u32 u32x4 __attribute__((ext_vector_type(4)));
typedef float f4 __attribute__((ext_vector_type(4)));
typedef float f2 __attribute__((ext_vector_type(2)));
typedef __fp16 h2 __attribute__((ext_vector_type(2)));

#define XB 8192               // x pairs: 64 kp * 32 rows * 4B
#define WB 16384              // w pairs: 128 k * 32 colpairs * 4B
#define BUFB (XB + WB)        // 24576; double buffer = 49152; overlay 65536

static __device__ __forceinline__ u32 pkcvt(float a, float b) {
  return __builtin_bit_cast(u32, __builtin_amdgcn_cvt_pkrtz(a, b));
}
static __device__ __forceinline__ u32 pkmax(u32 a, u32 b) {
  u32 d; asm("v_pk_max_u16 %0, %1, %2" : "=v"(d) : "v"(a), "v"(b)); return d;
}
// min(broadcast(x.lo), w) : out.lo=min(x.lo,w.lo), out.hi=min(x.lo,w.hi)
static __device__ __forceinline__ u32 pkmin_bl(u32 x, u32 w) {
  u32 d;
  asm("v_pk_min_u16 %0, %1, %2 op_sel:[0,0] op_sel_hi:[0,1]"
      : "=v"(d) : "v"(x), "v"(w));
  return d;
}
// min(broadcast(x.hi), w)
static __device__ __forceinline__ u32 pkmin_bh(u32 x, u32 w) {
  u32 d;
  asm("v_pk_min_u16 %0, %1, %2 op_sel:[1,0] op_sel_hi:[1,1]"
      : "=v"(d) : "v"(x), "v"(w));
  return d;
}
// max(v[lane], v[lane^32]) in every lane: permlane32_swap with a==b yields
// {lo,lo} and {hi,hi} (either swap direction works), then packed max.
static __device__ __forceinline__ u32 halfswap_max(u32 v) {
  u32 a = v, b = v;
  asm("v_permlane32_swap_b32 %0, %1" : "+v"(a), "+v"(b));
  return pkmax(a, b);
}

__global__ __launch_bounds__(1024, 4) void maxmin_v6(const float* __restrict__ X,
                                                     const float* __restrict__ W,
                                                     float* __restrict__ Out) {
  __shared__ __align__(16) char smem[65536];  // 48KB staging; 64KB epilogue overlay

  const int tid  = threadIdx.x;
  const int wv   = tid >> 6;   // wave 0..15
  const int lane = tid & 63;
  const int sh   = lane >> 5;  // half-wave = k-slice parity
  const int l5   = lane & 31;
  const int ty   = l5 >> 3;    // rows 8*ty .. 8*ty+7
  const int tx   = l5 & 7;     // cols 8*tx .. 8*tx+7 (colpairs 4*tx..4*tx+3)
  const int b0   = blockIdx.x * 32;
  const int o0   = blockIdx.y * 64;

  // x staging: r = tid>>5, kq = tid&31 -> coalesced 512B rows.
  const int xr  = tid >> 5;
  const int xkq = tid & 31;
  const float* xg = X + (b0 + xr) * 512 + xkq * 4;
  // LDS x write: pair kp=2kq (+1), addr = kp*128 + 4*(r ^ (kp&28)); the +1 pair
  // has the same xor -> second store at +128 (merges to ds_write2_b32).
  const int xw0 = (2 * xkq) * 128 + 4 * (xr ^ ((2 * xkq) & 28));

  // w staging: rows kk=tid>>4 (0..63) and kk+64; 4 cols per thread per row.
  const int wkk = tid >> 4;
  const int wc4 = tid & 15;
  const float* wg = W + wkk * 512 + o0 + wc4 * 4;
  const int ww0 = XB + wkk * 128 + wc4 * 8;

  // compute-side: slice = half-wave; per chunk this slice owns kpairs
  // kpb, kpb+1 (4 k). 32 slices x 2 kpairs = 64 kpairs/chunk.
  const int kpb = 4 * wv + 2 * sh;
  const int wro = XB + 16 * tx;

  u32 acc[8][4] = {};  // [row j][colpair cc], packed (col even, col odd)

  auto stage = [&](char* buf, f4 xv, f4 wa, f4 wb) {
    *(u32*)(buf + xw0)       = pkcvt(xv.x, xv.y);
    *(u32*)(buf + xw0 + 128) = pkcvt(xv.z, xv.w);
    u32x2 wpa = {pkcvt(wa.x, wa.y), pkcvt(wa.z, wa.w)};
    *(u32x2*)(buf + ww0) = wpa;
    u32x2 wpb = {pkcvt(wb.x, wb.y), pkcvt(wb.z, wb.w)};
    *(u32x2*)(buf + ww0 + 64 * 128) = wpb;
  };

  // prologue: stage chunk 0
  {
    f4 xv = *(const f4*)xg;
    f4 wa = *(const f4*)wg;
    f4 wb = *(const f4*)(wg + 64 * 512);
    stage(smem, xv, wa, wb);
  }
  __syncthreads();

  for (int c = 0; c < 4; ++c) {
    f4 nx = {}, na = {}, nb = {};
    if (c < 3) {  // prefetch next chunk before compute
      nx = *(const f4*)(xg + (c + 1) * 128);
      na = *(const f4*)(wg + (c + 1) * 128 * 512);
      nb = *(const f4*)(wg + (c + 1) * 128 * 512 + 64 * 512);
    }
    const char* buf = smem + (c & 1) * BUFB;
#pragma unroll
    for (int q = 0; q < 2; ++q) {
      const int kp = kpb + q;     // this half-wave's k-pair
      const int m  = kp & 28;     // same for both halves (kpb differs by 2)
      u32x4 x0 = *(const u32x4*)(buf + kp * 128 + 4 * ((8 * ty) ^ m));      // rows 8ty..+3
      u32x4 x1 = *(const u32x4*)(buf + kp * 128 + 4 * ((8 * ty + 4) ^ m));  // rows 8ty+4..+7
      u32x4 wl = *(const u32x4*)(buf + wro + (2 * kp) * 128);        // k even, 8 cols
      u32x4 wh = *(const u32x4*)(buf + wro + (2 * kp) * 128 + 128);  // k odd,  8 cols
#pragma unroll
      for (int j = 0; j < 4; ++j)
#pragma unroll
        for (int cc = 0; cc < 4; ++cc) {
          acc[j][cc]     = pkmax(acc[j][cc],     pkmin_bl(x0[j], wl[cc]));
          acc[j][cc]     = pkmax(acc[j][cc],     pkmin_bh(x0[j], wh[cc]));
          acc[4 + j][cc] = pkmax(acc[4 + j][cc], pkmin_bl(x1[j], wl[cc]));
          acc[4 + j][cc] = pkmax(acc[4 + j][cc], pkmin_bh(x1[j], wh[cc]));
        }
    }
    if (c < 3) stage(smem + ((c + 1) & 1) * BUFB, nx, na, nb);
    __syncthreads();
  }

  // fold the two half-wave k-slices in-register (VALU pipe): 32 -> 16 partials
#pragma unroll
  for (int j = 0; j < 8; ++j)
#pragma unroll
    for (int cc = 0; cc < 4; ++cc) acc[j][cc] = halfswap_max(acc[j][cc]);

  // epilogue: 16 wave-partials -> 64KB overlay [wv][row 0..31][colpair 0..31]
  if (sh == 0) {
#pragma unroll
    for (int j = 0; j < 8; ++j) {
      u32x4 v = {acc[j][0], acc[j][1], acc[j][2], acc[j][3]};
      *(u32x4*)(smem + wv * 4096 + (8 * ty + j) * 128 + tx * 16) = v;
    }
  }
  __syncthreads();

  const int row = tid >> 5;  // 0..31
  const int cp  = tid & 31;  // col-pair
  const int cb  = row * 128 + cp * 4;
  u32 m = *(const u32*)(smem + cb);
#pragma unroll
  for (int g = 1; g < 16; ++g) m = pkmax(m, *(const u32*)(smem + g * 4096 + cb));
  h2 hm = __builtin_bit_cast(h2, m);
  f2 o = {(float)hm.x, (float)hm.y};
  *(f2*)(Out + (b0 + row) * 512 + o0 + cp * 2) = o;
}

extern "C" void kernel_launch(void* const* d_in, const int* in_sizes, int n_in,
                              void* d_out, int out_size, void* d_ws, size_t ws_size,
                              hipStream_t stream) {
  const float* x = (const float*)d_in[0];
  const float* w = (const float*)d_in[1];
  float* out = (float*)d_out;
  (void)in_sizes; (void)n_in; (void)out_size; (void)d_ws; (void)ws_size;
  dim3 grid(1024 / 32, 512 / 64);  // 256 blocks = 1/CU, 16 waves each
  maxmin_v6<<<grid, 1024, 0, stream>>>(x, w, out);
}